// Round 4
// baseline (2297.455 us; speedup 1.0000x reference)
//
#include <hip/hip_runtime.h>

// Problem constants (match reference setup_inputs)
constexpr int NN = 50000;        // nodes
constexpr int NE = 1600000;      // edges
constexpr int NB = 8;            // batch
constexpr int M_ROWS = NN * NB;  // 400000 flattened rows (m = b*NN + n)

typedef unsigned short ushort;
typedef unsigned int uint;

__device__ __forceinline__ ushort f2bf(float f) {
  union { float f; uint u; } v;
  v.f = f;
  const uint r = v.u + 0x7fffu + ((v.u >> 16) & 1u);  // RNE
  return (ushort)(r >> 16);
}
__device__ __forceinline__ float bfhi(uint g) {  // high bf16 of a dword
  union { uint u; float f; } v;
  v.u = g & 0xffff0000u;
  return v.f;
}
__device__ __forceinline__ float bflo(uint g) {  // low bf16 of a dword
  union { uint u; float f; } v;
  v.u = g << 16;
  return v.f;
}

// ---------------------------------------------------------------------------
// CSR row_ptr from sorted edge_rows via per-row binary search (lower_bound).
// ---------------------------------------------------------------------------
__global__ __launch_bounds__(256) void rowptr_kernel(const int* __restrict__ rows,
                                                     int* __restrict__ row_ptr) {
  const int r = blockIdx.x * 256 + threadIdx.x;
  if (r > NN) return;
  int lo = 0, hi = NE;
  while (lo < hi) {
    const int mid = (lo + hi) >> 1;
    if (rows[mid] < r) lo = mid + 1;
    else hi = mid;
  }
  row_ptr[r] = lo;
}

// ---------------------------------------------------------------------------
// W [128][DOUT] fp32 -> Wt [DOUT][128] bf16 (tiny, once per launch).
// ---------------------------------------------------------------------------
__global__ __launch_bounds__(256) void wtrans_kernel(const float* __restrict__ W,
                                                     ushort* __restrict__ Wt,
                                                     int dout) {
  const int idx = blockIdx.x * 256 + threadIdx.x;  // over dout*128
  if (idx >= dout * 128) return;
  const int n = idx >> 7;
  const int k = idx & 127;
  Wt[idx] = f2bf(W[k * dout + n]);
}

// ---------------------------------------------------------------------------
// MFMA GEMM: S[M][DOUT] (bf16) = A[M][128] (fp32, converted in-kernel) @ W.
// Wt is pre-transposed bf16 [DOUT][128]. Block = 256 thr = 4 waves, 64 rows.
// (unchanged from round 3 — streaming-bound, not the bottleneck)
// ---------------------------------------------------------------------------
template <int DOUT>
__global__ __launch_bounds__(256) void gemm_mfma(const float* __restrict__ A,
                                                 const ushort* __restrict__ Wt,
                                                 ushort* __restrict__ S) {
  constexpr int NT = DOUT / 16;   // n-tiles per wave
  constexpr int LDK = 136;        // padded LDS row stride (ushorts)
  typedef __attribute__((ext_vector_type(8))) short bf16x8;
  typedef __attribute__((ext_vector_type(4))) float f32x4;

  __shared__ ushort As[64 * LDK];
  __shared__ ushort Ws[DOUT * LDK];

  const int t = threadIdx.x;
  const int w = t >> 6;
  const int l = t & 63;
  const size_t m0 = (size_t)blockIdx.x * 64;

  // ---- stage A tile: 64 rows x 128 fp32 -> bf16 LDS ----
  {
    const int row = t >> 2;
    const int c0 = (t & 3) * 32;
    const float* src = A + (m0 + row) * 128 + c0;
    ushort* dst = As + row * LDK + c0;
#pragma unroll
    for (int q = 0; q < 8; q++) {
      const float4 g = *(const float4*)(src + q * 4);
      dst[q * 4 + 0] = f2bf(g.x);
      dst[q * 4 + 1] = f2bf(g.y);
      dst[q * 4 + 2] = f2bf(g.z);
      dst[q * 4 + 3] = f2bf(g.w);
    }
  }
  // ---- stage Wt: DOUT x 128 bf16 -> LDS ----
  {
#pragma unroll
    for (int q = 0; q < (DOUT * 128) / (8 * 256); q++) {
      const int chunk = t + q * 256;
      const int n = chunk >> 4;
      const int off = (chunk & 15) * 8;
      *(uint4*)(Ws + n * LDK + off) = *(const uint4*)(Wt + n * 128 + off);
    }
  }
  __syncthreads();

  const int mrow = w * 16 + (l & 15);
  const int q8 = (l >> 4) * 8;

  bf16x8 a[4];
  const ushort* ap = As + mrow * LDK + q8;
#pragma unroll
  for (int ks = 0; ks < 4; ks++) a[ks] = *(const bf16x8*)(ap + ks * 32);

  f32x4 acc[NT];
#pragma unroll
  for (int nt = 0; nt < NT; nt++) acc[nt] = (f32x4)0.f;

#pragma unroll
  for (int nt = 0; nt < NT; nt++) {
    const ushort* bp = Ws + (nt * 16 + (l & 15)) * LDK + q8;
#pragma unroll
    for (int ks = 0; ks < 4; ks++) {
      const bf16x8 b = *(const bf16x8*)(bp + ks * 32);
      acc[nt] = __builtin_amdgcn_mfma_f32_16x16x32_bf16(a[ks], b, acc[nt], 0, 0, 0);
    }
  }

  // ---- epilogue: acc -> LDS (bf16) -> coalesced global stores ----
  __syncthreads();
  const int erow = w * 16 + (l >> 4) * 4;
  const int ecol = l & 15;
#pragma unroll
  for (int nt = 0; nt < NT; nt++)
#pragma unroll
    for (int r = 0; r < 4; r++)
      As[(erow + r) * LDK + nt * 16 + ecol] = f2bf(acc[nt][r]);
  __syncthreads();

#pragma unroll
  for (int q = 0; q < (64 * DOUT) / (8 * 256); q++) {
    const int chunk = t + q * 256;
    const int row = chunk / (DOUT / 8);
    const int off = (chunk % (DOUT / 8)) * 8;
    *(uint4*)(S + (m0 + row) * DOUT + off) = *(const uint4*)(As + row * LDK + off);
  }
}

// ---------------------------------------------------------------------------
// XCD-partitioned, column-quartered SpMM over bf16 S.
// blockIdx.x = ((q * (NN/4) + i) << 3) | b  -> b = x&7 pins batch to XCD
// (round-robin wg->XCD heuristic), so each XCD's random gathers stay inside
// one (batch, 32-col quarter) region of S = 3.2 MB < 4 MB per-XCD L2.
// Wave layout: 4 waves/block, wave = row r; within a wave 4 groups of 16
// lanes process 4 edges per step; lane loads 1 dword (2 bf16 cols).
// Cross-group reduce via shfl_xor(16/32); lanes 0..15 do fp32 epilogue.
// resid/out accessed nontemporally to keep the gather hot set in L2.
// out/resid NOT __restrict__ (layer 2 in-place; wave only touches own row).
// ---------------------------------------------------------------------------
template <int DOUT, bool RESID, bool SIGMOID>
__global__ __launch_bounds__(256) void spmm_kernel(const ushort* __restrict__ S,
                                                   const int* __restrict__ row_ptr,
                                                   const int* __restrict__ cols,
                                                   const float* __restrict__ vals,
                                                   const float* __restrict__ bias,
                                                   const float* resid,
                                                   float* out) {
  constexpr int NBLK = NN / 4;  // blocks per (q, b)

  const int x = blockIdx.x;
  const int b = x & 7;
  const int t_ = x >> 3;
  const int q = t_ / NBLK;
  const int i = t_ - q * NBLK;

  const int wave = threadIdx.x >> 6;
  const int lane = threadIdx.x & 63;
  const int h4 = lane >> 4;    // edge group 0..3
  const int l16 = lane & 15;   // column pair within quarter
  const int r = i * 4 + wave;
  const int jcol = q * 32 + l16 * 2;
  const ushort* Sb = S + (size_t)b * NN * DOUT + jcol;

  float a0 = 0.f, a1 = 0.f;

  const int e0 = row_ptr[r];
  const int e1 = row_ptr[r + 1];

  for (int e = e0; e < e1; e += 64) {
    const int n = min(64, e1 - e);
    int c = 0;
    float wv = 0.f;
    if (lane < n) {
      c = cols[e + lane];
      wv = vals[e + lane];
    }
    int ii = 0;
    for (; ii + 16 <= n; ii += 16) {  // 4 steps x 4 edges, 4 loads in flight
      int cs[4];
      float ws[4];
      uint g[4];
#pragma unroll
      for (int s = 0; s < 4; s++) {
        cs[s] = __shfl(c, ii + s * 4 + h4);
        ws[s] = __shfl(wv, ii + s * 4 + h4);
      }
#pragma unroll
      for (int s = 0; s < 4; s++)
        g[s] = *(const uint*)(Sb + (size_t)cs[s] * DOUT);
#pragma unroll
      for (int s = 0; s < 4; s++) {
        a0 += ws[s] * bflo(g[s]);
        a1 += ws[s] * bfhi(g[s]);
      }
    }
    for (; ii < n; ii += 4) {  // tail: idx <= 63 always; invalid edges have wv=0
      const int cs = __shfl(c, ii + h4);
      const float ws = __shfl(wv, ii + h4);
      const uint g = *(const uint*)(Sb + (size_t)cs * DOUT);
      a0 += ws * bflo(g);
      a1 += ws * bfhi(g);
    }
  }

  // reduce the 4 edge groups (lanes l16, l16+16, l16+32, l16+48)
  a0 += __shfl_xor(a0, 16);
  a0 += __shfl_xor(a0, 32);
  a1 += __shfl_xor(a1, 16);
  a1 += __shfl_xor(a1, 32);

  if (h4 == 0) {
    const size_t orow = (size_t)(b * NN + r) * DOUT + jcol;
    a0 += bias[jcol + 0];
    a1 += bias[jcol + 1];
    if constexpr (RESID) {
      a0 += __builtin_nontemporal_load(resid + orow + 0);
      a1 += __builtin_nontemporal_load(resid + orow + 1);
    }
    a0 = fmaxf(a0, 0.f);
    a1 = fmaxf(a1, 0.f);
    if constexpr (SIGMOID) {
      a0 = 1.f / (1.f + __expf(-a0));
      a1 = 1.f / (1.f + __expf(-a1));
    }
    __builtin_nontemporal_store(a0, out + orow + 0);
    __builtin_nontemporal_store(a1, out + orow + 1);
  }
}

// ---------------------------------------------------------------------------
// Launch. ws layout: row_ptr (256 KiB) | Wt1,Wt2,Wt3 bf16 | S bf16 102.4 MB |
// H fp32 204.8 MB.  ~308 MB total.
// ---------------------------------------------------------------------------
extern "C" void kernel_launch(void* const* d_in, const int* in_sizes, int n_in,
                              void* d_out, int out_size, void* d_ws, size_t ws_size,
                              hipStream_t stream) {
  const float* x = (const float*)d_in[0];
  const int* erows = (const int*)d_in[1];
  const int* ecols = (const int*)d_in[2];
  const float* evals = (const float*)d_in[3];
  const float* W1 = (const float*)d_in[4];
  const float* b1 = (const float*)d_in[5];
  const float* W2 = (const float*)d_in[6];
  const float* b2 = (const float*)d_in[7];
  const float* W3 = (const float*)d_in[8];
  const float* b3 = (const float*)d_in[9];

  char* ws = (char*)d_ws;
  int* row_ptr = (int*)ws;
  ushort* Wt1 = (ushort*)(ws + 0x40000);
  ushort* Wt2 = (ushort*)(ws + 0x48000);
  ushort* Wt3 = (ushort*)(ws + 0x50000);
  ushort* Sbf = (ushort*)(ws + 0x60000);
  float* H = (float*)(ws + 0x60000 + (size_t)M_ROWS * 128 * 2);

  rowptr_kernel<<<(NN + 256) / 256, 256, 0, stream>>>(erows, row_ptr);
  wtrans_kernel<<<(128 * 128) / 256, 256, 0, stream>>>(W1, Wt1, 128);
  wtrans_kernel<<<(128 * 128) / 256, 256, 0, stream>>>(W2, Wt2, 128);
  wtrans_kernel<<<(64 * 128) / 256, 256, 0, stream>>>(W3, Wt3, 64);

  const int sgrid128 = (NN / 4) * 8 * 4;  // (q,i) major, b in low 3 bits
  const int sgrid64 = (NN / 4) * 8 * 2;

  // Layer 1: S = x@W1; H = relu(spmm(S) + b1 + x)
  gemm_mfma<128><<<M_ROWS / 64, 256, 0, stream>>>(x, Wt1, Sbf);
  spmm_kernel<128, true, false><<<sgrid128, 256, 0, stream>>>(Sbf, row_ptr, ecols,
                                                              evals, b1, x, H);
  // Layer 2: S = H@W2; H = relu(spmm(S) + b2 + H)  (in place)
  gemm_mfma<128><<<M_ROWS / 64, 256, 0, stream>>>(H, Wt2, Sbf);
  spmm_kernel<128, true, false><<<sgrid128, 256, 0, stream>>>(Sbf, row_ptr, ecols,
                                                              evals, b2, H, H);
  // Layer 3: S = H@W3; out = sigmoid(relu(spmm(S) + b3))
  gemm_mfma<64><<<M_ROWS / 64, 256, 0, stream>>>(H, Wt3, Sbf);
  spmm_kernel<64, false, true><<<sgrid64, 256, 0, stream>>>(Sbf, row_ptr, ecols,
                                                            evals, b3, nullptr,
                                                            (float*)d_out);
}

// Round 5
// 1546.820 us; speedup vs baseline: 1.4853x; 1.4853x over previous
//
#include <hip/hip_runtime.h>

// Problem constants (match reference setup_inputs)
constexpr int NN = 50000;        // nodes
constexpr int NE = 1600000;      // edges
constexpr int NB = 8;            // batch
constexpr int M_ROWS = NN * NB;  // 400000 flattened rows (m = b*NN + n)

typedef unsigned short ushort;
typedef unsigned int uint;
typedef float f32x2v __attribute__((ext_vector_type(2)));
typedef float f32x4v __attribute__((ext_vector_type(4)));
typedef uint u32x4 __attribute__((ext_vector_type(4)));

__device__ __forceinline__ ushort f2bf(float f) {
  union { float f; uint u; } v;
  v.f = f;
  const uint r = v.u + 0x7fffu + ((v.u >> 16) & 1u);  // RNE
  return (ushort)(r >> 16);
}
__device__ __forceinline__ float bfhi(uint g) {  // high bf16 of a dword
  union { uint u; float f; } v;
  v.u = g & 0xffff0000u;
  return v.f;
}
__device__ __forceinline__ float bflo(uint g) {  // low bf16 of a dword
  union { uint u; float f; } v;
  v.u = g << 16;
  return v.f;
}

// ---------------------------------------------------------------------------
// CSR row_ptr from sorted edge_rows via per-row binary search (lower_bound).
// ---------------------------------------------------------------------------
__global__ __launch_bounds__(256) void rowptr_kernel(const int* __restrict__ rows,
                                                     int* __restrict__ row_ptr) {
  const int r = blockIdx.x * 256 + threadIdx.x;
  if (r > NN) return;
  int lo = 0, hi = NE;
  while (lo < hi) {
    const int mid = (lo + hi) >> 1;
    if (rows[mid] < r) lo = mid + 1;
    else hi = mid;
  }
  row_ptr[r] = lo;
}

// ---------------------------------------------------------------------------
// W [128][DOUT] fp32 -> Wt [DOUT][128] bf16 (tiny, once per launch).
// ---------------------------------------------------------------------------
__global__ __launch_bounds__(256) void wtrans_kernel(const float* __restrict__ W,
                                                     ushort* __restrict__ Wt,
                                                     int dout) {
  const int idx = blockIdx.x * 256 + threadIdx.x;  // over dout*128
  if (idx >= dout * 128) return;
  const int n = idx >> 7;
  const int k = idx & 127;
  Wt[idx] = f2bf(W[k * dout + n]);
}

// ---------------------------------------------------------------------------
// MFMA GEMM: S[M][DOUT] (bf16) = A[M][128] @ Wt^T.
// A is fp32 (layer 1, converted in-kernel) or bf16 (layers 2-3), selected by
// ABF16. A loads are NONTEMPORAL (streaming; keep LLC for the gather target).
// Block = 256 thr = 4 waves, 64 rows. mfma_f32_16x16x32_bf16, layouts per
// m89/m120-verified mappings. Epilogue via LDS for coalesced stores; S stores
// are CACHED (spmm gathers from S next).
// ---------------------------------------------------------------------------
template <int DOUT, bool ABF16>
__global__ __launch_bounds__(256) void gemm_mfma(const void* __restrict__ Av,
                                                 const ushort* __restrict__ Wt,
                                                 ushort* __restrict__ S) {
  constexpr int NT = DOUT / 16;   // n-tiles per wave
  constexpr int LDK = 136;        // padded LDS row stride (ushorts)
  typedef __attribute__((ext_vector_type(8))) short bf16x8;
  typedef __attribute__((ext_vector_type(4))) float f32x4;

  __shared__ ushort As[64 * LDK];
  __shared__ ushort Ws[DOUT * LDK];

  const int t = threadIdx.x;
  const int w = t >> 6;
  const int l = t & 63;
  const size_t m0 = (size_t)blockIdx.x * 64;

  // ---- stage A tile: 64 rows x 128 -> bf16 LDS ----
  if constexpr (ABF16) {
    const ushort* A = (const ushort*)Av;
#pragma unroll
    for (int q = 0; q < 4; q++) {
      const int chunk = t + q * 256;    // 0..1023 over 64 rows x 16 chunks
      const int row = chunk >> 4;
      const int off = (chunk & 15) * 8;
      *(u32x4*)(As + row * LDK + off) =
          __builtin_nontemporal_load((const u32x4*)(A + (m0 + row) * 128 + off));
    }
  } else {
    const float* A = (const float*)Av;
    const int row = t >> 2;
    const int c0 = (t & 3) * 32;
    const float* src = A + (m0 + row) * 128 + c0;
    ushort* dst = As + row * LDK + c0;
#pragma unroll
    for (int q = 0; q < 8; q++) {
      const f32x4v g = __builtin_nontemporal_load((const f32x4v*)(src + q * 4));
      dst[q * 4 + 0] = f2bf(g.x);
      dst[q * 4 + 1] = f2bf(g.y);
      dst[q * 4 + 2] = f2bf(g.z);
      dst[q * 4 + 3] = f2bf(g.w);
    }
  }
  // ---- stage Wt: DOUT x 128 bf16 -> LDS (cached; tiny, shared by all) ----
  {
#pragma unroll
    for (int q = 0; q < (DOUT * 128) / (8 * 256); q++) {
      const int chunk = t + q * 256;
      const int n = chunk >> 4;
      const int off = (chunk & 15) * 8;
      *(uint4*)(Ws + n * LDK + off) = *(const uint4*)(Wt + n * 128 + off);
    }
  }
  __syncthreads();

  const int mrow = w * 16 + (l & 15);
  const int q8 = (l >> 4) * 8;

  bf16x8 a[4];
  const ushort* ap = As + mrow * LDK + q8;
#pragma unroll
  for (int ks = 0; ks < 4; ks++) a[ks] = *(const bf16x8*)(ap + ks * 32);

  f32x4 acc[NT];
#pragma unroll
  for (int nt = 0; nt < NT; nt++) acc[nt] = (f32x4)0.f;

#pragma unroll
  for (int nt = 0; nt < NT; nt++) {
    const ushort* bp = Ws + (nt * 16 + (l & 15)) * LDK + q8;
#pragma unroll
    for (int ks = 0; ks < 4; ks++) {
      const bf16x8 b = *(const bf16x8*)(bp + ks * 32);
      acc[nt] = __builtin_amdgcn_mfma_f32_16x16x32_bf16(a[ks], b, acc[nt], 0, 0, 0);
    }
  }

  // ---- epilogue: acc -> LDS (bf16) -> coalesced global stores ----
  __syncthreads();
  const int erow = w * 16 + (l >> 4) * 4;
  const int ecol = l & 15;
#pragma unroll
  for (int nt = 0; nt < NT; nt++)
#pragma unroll
    for (int r = 0; r < 4; r++)
      As[(erow + r) * LDK + nt * 16 + ecol] = f2bf(acc[nt][r]);
  __syncthreads();

#pragma unroll
  for (int q = 0; q < (64 * DOUT) / (8 * 256); q++) {
    const int chunk = t + q * 256;
    const int row = chunk / (DOUT / 8);
    const int off = (chunk % (DOUT / 8)) * 8;
    *(uint4*)(S + (m0 + row) * DOUT + off) = *(const uint4*)(As + row * LDK + off);
  }
}

// ---------------------------------------------------------------------------
// Batch-sliced SpMM over bf16 S (round-3 structure: one wave per (row,batch),
// 256 B coalesced gather per edge) with nontemporal streaming for everything
// that is NOT the gather target, so the LLC retains S.
// RMODE: 0 = no residual, 1 = fp32 residual, 2 = bf16 residual.
// OBF16: output bf16 (H) vs fp32 (d_out).
// out/resid aliasing is safe: wave only touches its own output row.
// ---------------------------------------------------------------------------
template <int DOUT, int RMODE, bool SIGMOID, bool OBF16>
__global__ __launch_bounds__(256) void spmm_kernel(const ushort* __restrict__ S,
                                                   const int* __restrict__ row_ptr,
                                                   const int* __restrict__ cols,
                                                   const float* __restrict__ vals,
                                                   const float* __restrict__ bias,
                                                   const void* resid,
                                                   void* out) {
  constexpr int VEC = DOUT / 64;  // cols per lane: 2 (DOUT=128) or 1 (DOUT=64)

  const int wave = threadIdx.x >> 6;
  const int lane = threadIdx.x & 63;
  const int r = blockIdx.x * 4 + wave;  // NN % 4 == 0
  const int b = blockIdx.y;
  const int j = lane * VEC;
  const ushort* Sb = S + (size_t)b * NN * DOUT + j;

  float acc0 = 0.f, acc1 = 0.f;

  const int e0 = row_ptr[r];
  const int e1 = row_ptr[r + 1];

  for (int e = e0; e < e1; e += 64) {
    const int n = min(64, e1 - e);
    int c = 0;
    float wv = 0.f;
    if (lane < n) {
      c = __builtin_nontemporal_load(cols + e + lane);
      wv = __builtin_nontemporal_load(vals + e + lane);
    }
    int i = 0;
    for (; i + 4 <= n; i += 4) {
      const int c0 = __shfl(c, i + 0), c1 = __shfl(c, i + 1);
      const int c2 = __shfl(c, i + 2), c3 = __shfl(c, i + 3);
      const float w0 = __shfl(wv, i + 0), w1 = __shfl(wv, i + 1);
      const float w2 = __shfl(wv, i + 2), w3 = __shfl(wv, i + 3);
      if constexpr (VEC == 2) {
        const uint g0 = *(const uint*)(Sb + (size_t)c0 * DOUT);
        const uint g1 = *(const uint*)(Sb + (size_t)c1 * DOUT);
        const uint g2 = *(const uint*)(Sb + (size_t)c2 * DOUT);
        const uint g3 = *(const uint*)(Sb + (size_t)c3 * DOUT);
        acc0 += w0 * bflo(g0); acc1 += w0 * bfhi(g0);
        acc0 += w1 * bflo(g1); acc1 += w1 * bfhi(g1);
        acc0 += w2 * bflo(g2); acc1 += w2 * bfhi(g2);
        acc0 += w3 * bflo(g3); acc1 += w3 * bfhi(g3);
      } else {
        const ushort g0 = Sb[(size_t)c0 * DOUT];
        const ushort g1 = Sb[(size_t)c1 * DOUT];
        const ushort g2 = Sb[(size_t)c2 * DOUT];
        const ushort g3 = Sb[(size_t)c3 * DOUT];
        acc0 += w0 * bflo(g0);
        acc0 += w1 * bflo(g1);
        acc0 += w2 * bflo(g2);
        acc0 += w3 * bflo(g3);
      }
    }
    for (; i < n; i++) {
      const int ci = __shfl(c, i);
      const float wi = __shfl(wv, i);
      if constexpr (VEC == 2) {
        const uint g = *(const uint*)(Sb + (size_t)ci * DOUT);
        acc0 += wi * bflo(g); acc1 += wi * bfhi(g);
      } else {
        acc0 += wi * bflo(Sb[(size_t)ci * DOUT]);
      }
    }
  }

  // epilogue: bias + residual + relu (+ sigmoid); nontemporal writes
  const size_t orow = (size_t)(b * NN + r) * DOUT + j;
  if constexpr (VEC == 2) {
    acc0 += bias[j + 0];
    acc1 += bias[j + 1];
    if constexpr (RMODE == 1) {
      const f32x2v res =
          __builtin_nontemporal_load((const f32x2v*)((const float*)resid + orow));
      acc0 += res.x;
      acc1 += res.y;
    } else if constexpr (RMODE == 2) {
      const uint g =
          __builtin_nontemporal_load((const uint*)((const ushort*)resid + orow));
      acc0 += bflo(g);
      acc1 += bfhi(g);
    }
    acc0 = fmaxf(acc0, 0.f);
    acc1 = fmaxf(acc1, 0.f);
    if constexpr (SIGMOID) {
      acc0 = 1.f / (1.f + __expf(-acc0));
      acc1 = 1.f / (1.f + __expf(-acc1));
    }
    if constexpr (OBF16) {
      const uint o = (uint)f2bf(acc0) | ((uint)f2bf(acc1) << 16);
      __builtin_nontemporal_store(o, (uint*)((ushort*)out + orow));
    } else {
      f32x2v o;
      o.x = acc0;
      o.y = acc1;
      __builtin_nontemporal_store(o, (f32x2v*)((float*)out + orow));
    }
  } else {
    acc0 += bias[j];
    acc0 = fmaxf(acc0, 0.f);
    if constexpr (SIGMOID) acc0 = 1.f / (1.f + __expf(-acc0));
    __builtin_nontemporal_store(acc0, (float*)out + orow);
  }
}

// ---------------------------------------------------------------------------
// Launch. ws layout: row_ptr (0x40000) | Wt1 (0x48000) | Wt2 (0x50000) |
// Wt3 (0x54000..) | S bf16 102.4 MB (0x60000) | H bf16 102.4 MB. ~205 MB.
// ---------------------------------------------------------------------------
extern "C" void kernel_launch(void* const* d_in, const int* in_sizes, int n_in,
                              void* d_out, int out_size, void* d_ws, size_t ws_size,
                              hipStream_t stream) {
  const float* x = (const float*)d_in[0];
  const int* erows = (const int*)d_in[1];
  const int* ecols = (const int*)d_in[2];
  const float* evals = (const float*)d_in[3];
  const float* W1 = (const float*)d_in[4];
  const float* b1 = (const float*)d_in[5];
  const float* W2 = (const float*)d_in[6];
  const float* b2 = (const float*)d_in[7];
  const float* W3 = (const float*)d_in[8];
  const float* b3 = (const float*)d_in[9];

  char* ws = (char*)d_ws;
  int* row_ptr = (int*)ws;
  ushort* Wt1 = (ushort*)(ws + 0x40000);
  ushort* Wt2 = (ushort*)(ws + 0x48000);
  ushort* Wt3 = (ushort*)(ws + 0x50000);
  ushort* Sbf = (ushort*)(ws + 0x60000);
  ushort* H = (ushort*)(ws + 0x60000 + (size_t)M_ROWS * 128 * 2);

  rowptr_kernel<<<(NN + 256) / 256, 256, 0, stream>>>(erows, row_ptr);
  wtrans_kernel<<<(128 * 128) / 256, 256, 0, stream>>>(W1, Wt1, 128);
  wtrans_kernel<<<(128 * 128) / 256, 256, 0, stream>>>(W2, Wt2, 128);
  wtrans_kernel<<<(64 * 128) / 256, 256, 0, stream>>>(W3, Wt3, 64);

  const dim3 sgrid(NN / 4, NB);

  // Layer 1: S = x@W1; H = relu(spmm(S) + b1 + x)   [resid fp32, out bf16]
  gemm_mfma<128, false><<<M_ROWS / 64, 256, 0, stream>>>(x, Wt1, Sbf);
  spmm_kernel<128, 1, false, true><<<sgrid, 256, 0, stream>>>(
      Sbf, row_ptr, ecols, evals, b1, x, H);
  // Layer 2: S = H@W2; H = relu(spmm(S) + b2 + H)   [resid bf16, in place]
  gemm_mfma<128, true><<<M_ROWS / 64, 256, 0, stream>>>(H, Wt2, Sbf);
  spmm_kernel<128, 2, false, true><<<sgrid, 256, 0, stream>>>(
      Sbf, row_ptr, ecols, evals, b2, H, H);
  // Layer 3: S = H@W3; out = sigmoid(relu(spmm(S) + b3))   [out fp32]
  gemm_mfma<64, true><<<M_ROWS / 64, 256, 0, stream>>>(H, Wt3, Sbf);
  spmm_kernel<64, 0, true, false><<<sgrid, 256, 0, stream>>>(
      Sbf, row_ptr, ecols, evals, b3, nullptr, (float*)d_out);
}

// Round 6
// 1322.138 us; speedup vs baseline: 1.7377x; 1.1699x over previous
//
#include <hip/hip_runtime.h>

// Problem constants (match reference setup_inputs)
constexpr int NN = 50000;        // nodes
constexpr int NE = 1600000;      // edges
constexpr int NB = 8;            // batch
constexpr int M_ROWS = NN * NB;  // 400000 flattened rows (m = b*NN + n)

typedef unsigned short ushort;
typedef unsigned int uint;
typedef unsigned char uchar;
typedef float f32x2v __attribute__((ext_vector_type(2)));
typedef float f32x4v __attribute__((ext_vector_type(4)));
typedef uint u32x4 __attribute__((ext_vector_type(4)));

__device__ __forceinline__ ushort f2bf(float f) {
  union { float f; uint u; } v;
  v.f = f;
  const uint r = v.u + 0x7fffu + ((v.u >> 16) & 1u);  // RNE
  return (ushort)(r >> 16);
}
__device__ __forceinline__ float bfhi(uint g) {
  union { uint u; float f; } v;
  v.u = g & 0xffff0000u;
  return v.f;
}
__device__ __forceinline__ float bflo(uint g) {
  union { uint u; float f; } v;
  v.u = g << 16;
  return v.f;
}

// ---- fp8 e4m3fn <-> f32 (HW cvt if available; exact manual fallback) ----
__device__ __forceinline__ void fp8x2_to_f32(uint v, float& a, float& b) {
#if __has_builtin(__builtin_amdgcn_cvt_pk_f32_fp8)
  const f32x2v d = __builtin_amdgcn_cvt_pk_f32_fp8((int)v, false);
  a = d.x;
  b = d.y;
#else
  // exact: e4m3fn maps into f16 via <<7, then *2^8 (works for subnormals too)
  union { _Float16 h; ushort u; } c0, c1;
  c0.u = (ushort)(((v & 0x80u) << 8) | ((v & 0x7fu) << 7));
  c1.u = (ushort)(((v & 0x8000u)) | ((v & 0x7f00u) >> 1));
  a = (float)c0.h * 256.0f;
  b = (float)c1.h * 256.0f;
#endif
}
__device__ __forceinline__ uint f32_to_fp8(float x) {
#if __has_builtin(__builtin_amdgcn_cvt_pk_fp8_f32)
  return (uint)__builtin_amdgcn_cvt_pk_fp8_f32(x, x, 0, false) & 0xffu;
#else
  union { _Float16 h; ushort u; } c;
  c.h = (_Float16)(x * (1.0f / 256.0f));
  const uint h = c.u;
  uint r = h & 0x7fffu;
  r = (r + 0x3Fu + ((r >> 7) & 1u)) >> 7;  // RNE f16 -> e4m3 (scaled)
  if (r > 0x7Eu) r = 0x7Eu;                // saturate to 448
  return ((h >> 8) & 0x80u) | r;
#endif
}

// ---------------------------------------------------------------------------
// CSR row_ptr from sorted edge_rows via per-row binary search (lower_bound).
// ---------------------------------------------------------------------------
__global__ __launch_bounds__(256) void rowptr_kernel(const int* __restrict__ rows,
                                                     int* __restrict__ row_ptr) {
  const int r = blockIdx.x * 256 + threadIdx.x;
  if (r > NN) return;
  int lo = 0, hi = NE;
  while (lo < hi) {
    const int mid = (lo + hi) >> 1;
    if (rows[mid] < r) lo = mid + 1;
    else hi = mid;
  }
  row_ptr[r] = lo;
}

// ---------------------------------------------------------------------------
// W [128][DOUT] fp32 -> Wt [DOUT][128] bf16 (tiny, once per launch).
// ---------------------------------------------------------------------------
__global__ __launch_bounds__(256) void wtrans_kernel(const float* __restrict__ W,
                                                     ushort* __restrict__ Wt,
                                                     int dout) {
  const int idx = blockIdx.x * 256 + threadIdx.x;
  if (idx >= dout * 128) return;
  const int n = idx >> 7;
  const int k = idx & 127;
  Wt[idx] = f2bf(W[k * dout + n]);
}

// ---------------------------------------------------------------------------
// MFMA GEMM: S (fp8 e4m3) = A[M][128] @ Wt^T.  A fp32 (ABF16=0) or bf16.
// Block = 256 thr = 4 waves, 64 rows. mfma_f32_16x16x32_bf16 (m89 layouts).
// PAIR3: store S3[pair][node][ (b&1)*64 + col ] (batch-pair packed, layer 3);
// else flat S[m][DOUT]. Epilogue via byte-LDS for coalesced 16B stores.
// ---------------------------------------------------------------------------
template <int DOUT, bool ABF16, bool PAIR3>
__global__ __launch_bounds__(256) void gemm_mfma(const void* __restrict__ Av,
                                                 const ushort* __restrict__ Wt,
                                                 uchar* __restrict__ S) {
  constexpr int NT = DOUT / 16;
  constexpr int LDK = 136;            // bf16 LDS row stride
  constexpr int LB = DOUT + 16;       // byte-epilogue row stride (16B-aligned)
  typedef __attribute__((ext_vector_type(8))) short bf16x8;
  typedef __attribute__((ext_vector_type(4))) float f32x4;

  __shared__ ushort As[64 * LDK];     // 17408 B; reused as byte buffer in epilogue
  __shared__ ushort Ws[DOUT * LDK];

  const int t = threadIdx.x;
  const int w = t >> 6;
  const int l = t & 63;
  const size_t m0 = (size_t)blockIdx.x * 64;

  // ---- stage A tile: 64 rows x 128 -> bf16 LDS ----
  if constexpr (ABF16) {
    const ushort* A = (const ushort*)Av;
#pragma unroll
    for (int q = 0; q < 4; q++) {
      const int chunk = t + q * 256;
      const int row = chunk >> 4;
      const int off = (chunk & 15) * 8;
      *(u32x4*)(As + row * LDK + off) =
          __builtin_nontemporal_load((const u32x4*)(A + (m0 + row) * 128 + off));
    }
  } else {
    const float* A = (const float*)Av;
    const int row = t >> 2;
    const int c0 = (t & 3) * 32;
    const float* src = A + (m0 + row) * 128 + c0;
    ushort* dst = As + row * LDK + c0;
#pragma unroll
    for (int q = 0; q < 8; q++) {
      const f32x4v g = __builtin_nontemporal_load((const f32x4v*)(src + q * 4));
      dst[q * 4 + 0] = f2bf(g.x);
      dst[q * 4 + 1] = f2bf(g.y);
      dst[q * 4 + 2] = f2bf(g.z);
      dst[q * 4 + 3] = f2bf(g.w);
    }
  }
  // ---- stage Wt: DOUT x 128 bf16 -> LDS ----
  {
#pragma unroll
    for (int q = 0; q < (DOUT * 128) / (8 * 256); q++) {
      const int chunk = t + q * 256;
      const int n = chunk >> 4;
      const int off = (chunk & 15) * 8;
      *(uint4*)(Ws + n * LDK + off) = *(const uint4*)(Wt + n * 128 + off);
    }
  }
  __syncthreads();

  const int mrow = w * 16 + (l & 15);
  const int q8 = (l >> 4) * 8;

  bf16x8 a[4];
  const ushort* ap = As + mrow * LDK + q8;
#pragma unroll
  for (int ks = 0; ks < 4; ks++) a[ks] = *(const bf16x8*)(ap + ks * 32);

  f32x4 acc[NT];
#pragma unroll
  for (int nt = 0; nt < NT; nt++) acc[nt] = (f32x4)0.f;

#pragma unroll
  for (int nt = 0; nt < NT; nt++) {
    const ushort* bp = Ws + (nt * 16 + (l & 15)) * LDK + q8;
#pragma unroll
    for (int ks = 0; ks < 4; ks++) {
      const bf16x8 b = *(const bf16x8*)(bp + ks * 32);
      acc[nt] = __builtin_amdgcn_mfma_f32_16x16x32_bf16(a[ks], b, acc[nt], 0, 0, 0);
    }
  }

  // ---- epilogue: acc -> fp8 byte-LDS -> coalesced 16B global stores ----
  __syncthreads();
  uchar* Ab = (uchar*)As;
  const int erow = w * 16 + (l >> 4) * 4;
  const int ecol = l & 15;
#pragma unroll
  for (int nt = 0; nt < NT; nt++)
#pragma unroll
    for (int r = 0; r < 4; r++)
      Ab[(erow + r) * LB + nt * 16 + ecol] = (uchar)f32_to_fp8(acc[nt][r]);
  __syncthreads();

#pragma unroll
  for (int q = 0; q < (64 * DOUT) / (16 * 256); q++) {
    const int chunk = t + q * 256;
    const int row = chunk / (DOUT / 16);
    const int off = (chunk % (DOUT / 16)) * 16;
    const uint4 v = *(const uint4*)(Ab + row * LB + off);
    if constexpr (PAIR3) {
      const int m = (int)m0 + row;
      const int b = m / NN;
      const int n = m - b * NN;
      *(uint4*)(S + ((size_t)(b >> 1) * NN + n) * 128 + (b & 1) * 64 + off) = v;
    } else {
      *(uint4*)(S + (m0 + row) * DOUT + off) = v;
    }
  }
}

// ---------------------------------------------------------------------------
// SpMM over fp8 S, DOUT=128, batch-sliced (grid (NN/4, NB), x-fastest).
// One wave per (row, batch); lane loads ushort (2 fp8 cols) -> 128 B/edge,
// one fully-used cache line. RMODE: 0 none, 1 fp32 resid, 2 bf16 resid.
// ---------------------------------------------------------------------------
template <int RMODE, bool OBF16>
__global__ __launch_bounds__(256) void spmm128_kernel(
    const uchar* __restrict__ S, const int* __restrict__ row_ptr,
    const int* __restrict__ cols, const float* __restrict__ vals,
    const float* __restrict__ bias, const void* resid, void* out) {
  const int wave = threadIdx.x >> 6;
  const int lane = threadIdx.x & 63;
  const int r = blockIdx.x * 4 + wave;  // NN % 4 == 0
  const int b = blockIdx.y;
  const int j = lane * 2;
  const uchar* Sb = S + (size_t)b * NN * 128 + j;

  float acc0 = 0.f, acc1 = 0.f;

  const int e0 = row_ptr[r];
  const int e1 = row_ptr[r + 1];

  for (int e = e0; e < e1; e += 64) {
    const int n = min(64, e1 - e);
    int c = 0;
    float wv = 0.f;
    if (lane < n) {
      c = __builtin_nontemporal_load(cols + e + lane);
      wv = __builtin_nontemporal_load(vals + e + lane);
    }
    int i = 0;
    for (; i + 4 <= n; i += 4) {
      int cc[4];
      float ww[4];
      uint gg[4];
#pragma unroll
      for (int s = 0; s < 4; s++) {
        cc[s] = __shfl(c, i + s);
        ww[s] = __shfl(wv, i + s);
      }
#pragma unroll
      for (int s = 0; s < 4; s++)
        gg[s] = *(const ushort*)(Sb + (size_t)cc[s] * 128);
#pragma unroll
      for (int s = 0; s < 4; s++) {
        float va, vb;
        fp8x2_to_f32(gg[s], va, vb);
        acc0 += ww[s] * va;
        acc1 += ww[s] * vb;
      }
    }
    for (; i < n; i++) {
      const int ci = __shfl(c, i);
      const float wi = __shfl(wv, i);
      const uint g = *(const ushort*)(Sb + (size_t)ci * 128);
      float va, vb;
      fp8x2_to_f32(g, va, vb);
      acc0 += wi * va;
      acc1 += wi * vb;
    }
  }

  const size_t orow = (size_t)(b * NN + r) * 128 + j;
  acc0 += bias[j + 0];
  acc1 += bias[j + 1];
  if constexpr (RMODE == 1) {
    const f32x2v res =
        __builtin_nontemporal_load((const f32x2v*)((const float*)resid + orow));
    acc0 += res.x;
    acc1 += res.y;
  } else if constexpr (RMODE == 2) {
    const uint g =
        __builtin_nontemporal_load((const uint*)((const ushort*)resid + orow));
    acc0 += bflo(g);
    acc1 += bfhi(g);
  }
  acc0 = fmaxf(acc0, 0.f);
  acc1 = fmaxf(acc1, 0.f);
  if constexpr (OBF16) {
    const uint o = (uint)f2bf(acc0) | ((uint)f2bf(acc1) << 16);
    __builtin_nontemporal_store(o, (uint*)((ushort*)out + orow));
  } else {
    f32x2v o;
    o.x = acc0;
    o.y = acc1;
    __builtin_nontemporal_store(o, (f32x2v*)((float*)out + orow));
  }
}

// ---------------------------------------------------------------------------
// Layer-3 SpMM over batch-pair-packed fp8 S3 (grid (NN/4, 4)).
// S3[pair][node][128]: bytes 0..63 = batch 2p cols, 64..127 = batch 2p+1.
// One wave serves BOTH batches of the pair per edge: lane reads ushort at
// byte offset lane*2 -> 128 B/edge, one fully-used line, 2 batches amortized.
// Epilogue: b = 2p + (lane>>5), jcol = (lane&31)*2; sigmoid(relu(.+bias)).
// ---------------------------------------------------------------------------
__global__ __launch_bounds__(256) void spmm64p_kernel(
    const uchar* __restrict__ S3, const int* __restrict__ row_ptr,
    const int* __restrict__ cols, const float* __restrict__ vals,
    const float* __restrict__ bias, float* __restrict__ out) {
  const int wave = threadIdx.x >> 6;
  const int lane = threadIdx.x & 63;
  const int r = blockIdx.x * 4 + wave;
  const int p = blockIdx.y;
  const uchar* Sb = S3 + (size_t)p * NN * 128 + lane * 2;

  float acc0 = 0.f, acc1 = 0.f;

  const int e0 = row_ptr[r];
  const int e1 = row_ptr[r + 1];

  for (int e = e0; e < e1; e += 64) {
    const int n = min(64, e1 - e);
    int c = 0;
    float wv = 0.f;
    if (lane < n) {
      c = __builtin_nontemporal_load(cols + e + lane);
      wv = __builtin_nontemporal_load(vals + e + lane);
    }
    int i = 0;
    for (; i + 4 <= n; i += 4) {
      int cc[4];
      float ww[4];
      uint gg[4];
#pragma unroll
      for (int s = 0; s < 4; s++) {
        cc[s] = __shfl(c, i + s);
        ww[s] = __shfl(wv, i + s);
      }
#pragma unroll
      for (int s = 0; s < 4; s++)
        gg[s] = *(const ushort*)(Sb + (size_t)cc[s] * 128);
#pragma unroll
      for (int s = 0; s < 4; s++) {
        float va, vb;
        fp8x2_to_f32(gg[s], va, vb);
        acc0 += ww[s] * va;
        acc1 += ww[s] * vb;
      }
    }
    for (; i < n; i++) {
      const int ci = __shfl(c, i);
      const float wi = __shfl(wv, i);
      const uint g = *(const ushort*)(Sb + (size_t)ci * 128);
      float va, vb;
      fp8x2_to_f32(g, va, vb);
      acc0 += wi * va;
      acc1 += wi * vb;
    }
  }

  const int b = p * 2 + (lane >> 5);
  const int jcol = (lane & 31) * 2;
  const size_t orow = (size_t)(b * NN + r) * 64 + jcol;
  acc0 += bias[jcol + 0];
  acc1 += bias[jcol + 1];
  acc0 = fmaxf(acc0, 0.f);
  acc1 = fmaxf(acc1, 0.f);
  acc0 = 1.f / (1.f + __expf(-acc0));
  acc1 = 1.f / (1.f + __expf(-acc1));
  f32x2v o;
  o.x = acc0;
  o.y = acc1;
  __builtin_nontemporal_store(o, (f32x2v*)(out + orow));
}

// ---------------------------------------------------------------------------
// Launch. ws: row_ptr(0x40000) | Wt1(0x48000) | Wt2(0x50000) | Wt3(0x54000)
// | S fp8 51.2 MB (0x60000; layer-3 pair layout reuses it, 25.6 MB)
// | H bf16 102.4 MB.  ~154 MB total.
// ---------------------------------------------------------------------------
extern "C" void kernel_launch(void* const* d_in, const int* in_sizes, int n_in,
                              void* d_out, int out_size, void* d_ws, size_t ws_size,
                              hipStream_t stream) {
  const float* x = (const float*)d_in[0];
  const int* erows = (const int*)d_in[1];
  const int* ecols = (const int*)d_in[2];
  const float* evals = (const float*)d_in[3];
  const float* W1 = (const float*)d_in[4];
  const float* b1 = (const float*)d_in[5];
  const float* W2 = (const float*)d_in[6];
  const float* b2 = (const float*)d_in[7];
  const float* W3 = (const float*)d_in[8];
  const float* b3 = (const float*)d_in[9];

  char* ws = (char*)d_ws;
  int* row_ptr = (int*)ws;
  ushort* Wt1 = (ushort*)(ws + 0x40000);
  ushort* Wt2 = (ushort*)(ws + 0x48000);
  ushort* Wt3 = (ushort*)(ws + 0x50000);
  uchar* Sf8 = (uchar*)(ws + 0x60000);
  ushort* H = (ushort*)(ws + 0x60000 + (size_t)M_ROWS * 128);

  rowptr_kernel<<<(NN + 256) / 256, 256, 0, stream>>>(erows, row_ptr);
  wtrans_kernel<<<(128 * 128) / 256, 256, 0, stream>>>(W1, Wt1, 128);
  wtrans_kernel<<<(128 * 128) / 256, 256, 0, stream>>>(W2, Wt2, 128);
  wtrans_kernel<<<(64 * 128) / 256, 256, 0, stream>>>(W3, Wt3, 64);

  const dim3 sgrid128(NN / 4, NB);
  const dim3 sgrid64(NN / 4, NB / 2);

  // Layer 1: S = x@W1 (fp8); H = relu(spmm(S) + b1 + x)   [resid fp32 -> bf16]
  gemm_mfma<128, false, false><<<M_ROWS / 64, 256, 0, stream>>>(x, Wt1, Sf8);
  spmm128_kernel<1, true><<<sgrid128, 256, 0, stream>>>(Sf8, row_ptr, ecols,
                                                        evals, b1, x, H);
  // Layer 2: S = H@W2 (fp8); H = relu(spmm(S) + b2 + H)   [bf16, in place]
  gemm_mfma<128, true, false><<<M_ROWS / 64, 256, 0, stream>>>(H, Wt2, Sf8);
  spmm128_kernel<2, true><<<sgrid128, 256, 0, stream>>>(Sf8, row_ptr, ecols,
                                                        evals, b2, H, H);
  // Layer 3: S3 = H@W3 (fp8, pair-packed); out = sigmoid(relu(spmm(S3) + b3))
  gemm_mfma<64, true, true><<<M_ROWS / 64, 256, 0, stream>>>(H, Wt3, Sf8);
  spmm64p_kernel<<<sgrid64, 256, 0, stream>>>(Sf8, row_ptr, ecols, evals, b3,
                                              (float*)d_out);
}

// Round 7
// 982.863 us; speedup vs baseline: 2.3375x; 1.3452x over previous
//
#include <hip/hip_runtime.h>

// Problem constants (match reference setup_inputs)
constexpr int NN = 50000;        // nodes
constexpr int NE = 1600000;      // edges
constexpr int NB = 8;            // batch
constexpr int M_ROWS = NN * NB;  // 400000 flattened rows (m = b*NN + n)

typedef unsigned short ushort;
typedef unsigned int uint;
typedef unsigned char uchar;
typedef float f32x2v __attribute__((ext_vector_type(2)));
typedef float f32x4v __attribute__((ext_vector_type(4)));
typedef uint u32x4 __attribute__((ext_vector_type(4)));
typedef uint u32x2 __attribute__((ext_vector_type(2)));

__device__ __forceinline__ ushort f2bf(float f) {
  union { float f; uint u; } v;
  v.f = f;
  const uint r = v.u + 0x7fffu + ((v.u >> 16) & 1u);  // RNE
  return (ushort)(r >> 16);
}
__device__ __forceinline__ float bfhi(uint g) {
  union { uint u; float f; } v;
  v.u = g & 0xffff0000u;
  return v.f;
}
__device__ __forceinline__ float bflo(uint g) {
  union { uint u; float f; } v;
  v.u = g << 16;
  return v.f;
}

// ---- fp8 e4m3fn <-> f32 (HW cvt if available; exact manual fallback) ----
__device__ __forceinline__ void fp8x4_to_f32(uint v, float& a, float& b,
                                             float& c, float& d) {
#if __has_builtin(__builtin_amdgcn_cvt_pk_f32_fp8)
  const f32x2v lo = __builtin_amdgcn_cvt_pk_f32_fp8((int)v, false);
  const f32x2v hi = __builtin_amdgcn_cvt_pk_f32_fp8((int)v, true);
  a = lo.x; b = lo.y; c = hi.x; d = hi.y;
#else
  union { _Float16 h; ushort u; } c0, c1, c2, c3;
  c0.u = (ushort)(((v & 0x80u) << 8) | ((v & 0x7fu) << 7));
  c1.u = (ushort)(((v & 0x8000u)) | ((v & 0x7f00u) >> 1));
  c2.u = (ushort)(((v >> 16) & 0x8000u ? 0x8000u : 0u) |
                  (((v >> 16) & 0x7fu) << 7));
  c3.u = (ushort)((((v >> 24) & 0x80u) << 8) | (((v >> 24) & 0x7fu) << 7));
  // note: c2 uses bits 16..23: sign bit is bit 23
  c2.u = (ushort)((((v >> 16) & 0x80u) << 8) | (((v >> 16) & 0x7fu) << 7));
  a = (float)c0.h * 256.0f;
  b = (float)c1.h * 256.0f;
  c = (float)c2.h * 256.0f;
  d = (float)c3.h * 256.0f;
#endif
}
__device__ __forceinline__ uint f32_to_fp8(float x) {
#if __has_builtin(__builtin_amdgcn_cvt_pk_fp8_f32)
  return (uint)__builtin_amdgcn_cvt_pk_fp8_f32(x, x, 0, false) & 0xffu;
#else
  union { _Float16 h; ushort u; } c;
  c.h = (_Float16)(x * (1.0f / 256.0f));
  const uint h = c.u;
  uint r = h & 0x7fffu;
  r = (r + 0x3Fu + ((r >> 7) & 1u)) >> 7;  // RNE f16 -> e4m3 (scaled)
  if (r > 0x7Eu) r = 0x7Eu;                // saturate to 448
  return ((h >> 8) & 0x80u) | r;
#endif
}

// ---------------------------------------------------------------------------
// CSR row_ptr from sorted edge_rows via per-row binary search (lower_bound).
// ---------------------------------------------------------------------------
__global__ __launch_bounds__(256) void rowptr_kernel(const int* __restrict__ rows,
                                                     int* __restrict__ row_ptr) {
  const int r = blockIdx.x * 256 + threadIdx.x;
  if (r > NN) return;
  int lo = 0, hi = NE;
  while (lo < hi) {
    const int mid = (lo + hi) >> 1;
    if (rows[mid] < r) lo = mid + 1;
    else hi = mid;
  }
  row_ptr[r] = lo;
}

// ---------------------------------------------------------------------------
// W [128][DOUT] fp32 -> Wt [DOUT][128] bf16 (tiny, once per launch).
// ---------------------------------------------------------------------------
__global__ __launch_bounds__(256) void wtrans_kernel(const float* __restrict__ W,
                                                     ushort* __restrict__ Wt,
                                                     int dout) {
  const int idx = blockIdx.x * 256 + threadIdx.x;
  if (idx >= dout * 128) return;
  const int n = idx >> 7;
  const int k = idx & 127;
  Wt[idx] = f2bf(W[k * dout + n]);
}

// ---------------------------------------------------------------------------
// MFMA GEMM: S (fp8 e4m3, batch-packed) = A[M][128] @ Wt^T.
// A fp32 (ABF16=0) or bf16. Block = 256 thr = 4 waves, 64 rows.
// S layout: PACK batches share a 256 B group:
//   S[(b/PACK)*NN + n][256] with slot (b%PACK)*DOUT + col.   PACK*DOUT == 256.
// Epilogue via byte-LDS for coalesced 16B stores.
// ---------------------------------------------------------------------------
template <int DOUT, bool ABF16>
__global__ __launch_bounds__(256) void gemm_mfma(const void* __restrict__ Av,
                                                 const ushort* __restrict__ Wt,
                                                 uchar* __restrict__ S) {
  constexpr int PACK = 256 / DOUT;
  constexpr int NT = DOUT / 16;
  constexpr int LDK = 136;            // bf16 LDS row stride
  constexpr int LB = DOUT + 16;       // byte-epilogue row stride
  typedef __attribute__((ext_vector_type(8))) short bf16x8;
  typedef __attribute__((ext_vector_type(4))) float f32x4;

  __shared__ ushort As[64 * LDK];     // reused as byte buffer in epilogue
  __shared__ ushort Ws[DOUT * LDK];

  const int t = threadIdx.x;
  const int w = t >> 6;
  const int l = t & 63;
  const size_t m0 = (size_t)blockIdx.x * 64;

  // ---- stage A tile: 64 rows x 128 -> bf16 LDS ----
  if constexpr (ABF16) {
    const ushort* A = (const ushort*)Av;
#pragma unroll
    for (int q = 0; q < 4; q++) {
      const int chunk = t + q * 256;
      const int row = chunk >> 4;
      const int off = (chunk & 15) * 8;
      *(u32x4*)(As + row * LDK + off) =
          __builtin_nontemporal_load((const u32x4*)(A + (m0 + row) * 128 + off));
    }
  } else {
    const float* A = (const float*)Av;
    const int row = t >> 2;
    const int c0 = (t & 3) * 32;
    const float* src = A + (m0 + row) * 128 + c0;
    ushort* dst = As + row * LDK + c0;
#pragma unroll
    for (int q = 0; q < 8; q++) {
      const f32x4v g = __builtin_nontemporal_load((const f32x4v*)(src + q * 4));
      dst[q * 4 + 0] = f2bf(g.x);
      dst[q * 4 + 1] = f2bf(g.y);
      dst[q * 4 + 2] = f2bf(g.z);
      dst[q * 4 + 3] = f2bf(g.w);
    }
  }
  // ---- stage Wt: DOUT x 128 bf16 -> LDS ----
  {
#pragma unroll
    for (int q = 0; q < (DOUT * 128) / (8 * 256); q++) {
      const int chunk = t + q * 256;
      const int n = chunk >> 4;
      const int off = (chunk & 15) * 8;
      *(uint4*)(Ws + n * LDK + off) = *(const uint4*)(Wt + n * 128 + off);
    }
  }
  __syncthreads();

  const int mrow = w * 16 + (l & 15);
  const int q8 = (l >> 4) * 8;

  bf16x8 a[4];
  const ushort* ap = As + mrow * LDK + q8;
#pragma unroll
  for (int ks = 0; ks < 4; ks++) a[ks] = *(const bf16x8*)(ap + ks * 32);

  f32x4 acc[NT];
#pragma unroll
  for (int nt = 0; nt < NT; nt++) acc[nt] = (f32x4)0.f;

#pragma unroll
  for (int nt = 0; nt < NT; nt++) {
    const ushort* bp = Ws + (nt * 16 + (l & 15)) * LDK + q8;
#pragma unroll
    for (int ks = 0; ks < 4; ks++) {
      const bf16x8 b = *(const bf16x8*)(bp + ks * 32);
      acc[nt] = __builtin_amdgcn_mfma_f32_16x16x32_bf16(a[ks], b, acc[nt], 0, 0, 0);
    }
  }

  // ---- epilogue: acc -> fp8 byte-LDS -> packed 16B global stores ----
  __syncthreads();
  uchar* Ab = (uchar*)As;
  const int erow = w * 16 + (l >> 4) * 4;
  const int ecol = l & 15;
#pragma unroll
  for (int nt = 0; nt < NT; nt++)
#pragma unroll
    for (int r = 0; r < 4; r++)
      Ab[(erow + r) * LB + nt * 16 + ecol] = (uchar)f32_to_fp8(acc[nt][r]);
  __syncthreads();

#pragma unroll
  for (int q = 0; q < (64 * DOUT) / (16 * 256); q++) {
    const int chunk = t + q * 256;
    const int row = chunk / (DOUT / 16);
    const int off = (chunk % (DOUT / 16)) * 16;
    const uint4 v = *(const uint4*)(Ab + row * LB + off);
    const int m = (int)m0 + row;
    const int b = m / NN;
    const int n = m - b * NN;
    *(uint4*)(S + ((size_t)(b / PACK) * NN + n) * 256 + (b % PACK) * DOUT + off) = v;
  }
}

// ---------------------------------------------------------------------------
// Batch-packed SpMM over fp8 S. PACK batches per 256 B group; one wave per
// (row r, batch group). grid = (NN/4, NB/PACK), x-fastest keeps the hot
// gather slice (12.8 MB) contiguous in time.
// Per edge: ONE 256 B request (2 fully-used lines); lane loads uint = 4 fp8.
// Lane layout: bg = lane/(64/PACK) -> batch in group; j = (lane%(64/PACK))*4.
// 8 edges unrolled in flight for MLP. RMODE: 0 none, 1 fp32, 2 bf16 resid.
// ---------------------------------------------------------------------------
template <int PACK, int RMODE, bool SIGMOID, bool OBF16>
__global__ __launch_bounds__(256) void spmm_kernel(
    const uchar* __restrict__ S, const int* __restrict__ row_ptr,
    const int* __restrict__ cols, const float* __restrict__ vals,
    const float* __restrict__ bias, const void* resid, void* out) {
  constexpr int DOUT = 256 / PACK;
  constexpr int LPB = 64 / PACK;  // lanes per batch

  const int wave = threadIdx.x >> 6;
  const int lane = threadIdx.x & 63;
  const int r = blockIdx.x * 4 + wave;  // NN % 4 == 0
  const int bg = lane / LPB;
  const int j = (lane % LPB) * 4;
  const int b = blockIdx.y * PACK + bg;
  const uchar* Sb = S + (size_t)blockIdx.y * NN * 256 + lane * 4;

  float a0 = 0.f, a1 = 0.f, a2 = 0.f, a3 = 0.f;

  const int e0 = row_ptr[r];
  const int e1 = row_ptr[r + 1];

  for (int e = e0; e < e1; e += 64) {
    const int n = min(64, e1 - e);
    int c = 0;
    float wv = 0.f;
    if (lane < n) {
      c = __builtin_nontemporal_load(cols + e + lane);
      wv = __builtin_nontemporal_load(vals + e + lane);
    }
    int i = 0;
    for (; i + 8 <= n; i += 8) {
      int cc[8];
      float ww[8];
      uint gg[8];
#pragma unroll
      for (int s = 0; s < 8; s++) {
        cc[s] = __shfl(c, i + s);
        ww[s] = __shfl(wv, i + s);
      }
#pragma unroll
      for (int s = 0; s < 8; s++)
        gg[s] = *(const uint*)(Sb + (size_t)cc[s] * 256);
#pragma unroll
      for (int s = 0; s < 8; s++) {
        float v0, v1, v2, v3;
        fp8x4_to_f32(gg[s], v0, v1, v2, v3);
        a0 += ww[s] * v0;
        a1 += ww[s] * v1;
        a2 += ww[s] * v2;
        a3 += ww[s] * v3;
      }
    }
    for (; i < n; i++) {
      const int ci = __shfl(c, i);
      const float wi = __shfl(wv, i);
      const uint g = *(const uint*)(Sb + (size_t)ci * 256);
      float v0, v1, v2, v3;
      fp8x4_to_f32(g, v0, v1, v2, v3);
      a0 += wi * v0;
      a1 += wi * v1;
      a2 += wi * v2;
      a3 += wi * v3;
    }
  }

  // epilogue: bias + residual + relu (+ sigmoid)
  const size_t orow = (size_t)(b * NN + r) * DOUT + j;
  const f32x4v bb = *(const f32x4v*)(bias + j);
  a0 += bb.x;
  a1 += bb.y;
  a2 += bb.z;
  a3 += bb.w;
  if constexpr (RMODE == 1) {
    const f32x4v res =
        __builtin_nontemporal_load((const f32x4v*)((const float*)resid + orow));
    a0 += res.x;
    a1 += res.y;
    a2 += res.z;
    a3 += res.w;
  } else if constexpr (RMODE == 2) {
    const u32x2 g =
        __builtin_nontemporal_load((const u32x2*)((const ushort*)resid + orow));
    a0 += bflo(g.x);
    a1 += bfhi(g.x);
    a2 += bflo(g.y);
    a3 += bfhi(g.y);
  }
  a0 = fmaxf(a0, 0.f);
  a1 = fmaxf(a1, 0.f);
  a2 = fmaxf(a2, 0.f);
  a3 = fmaxf(a3, 0.f);
  if constexpr (SIGMOID) {
    a0 = 1.f / (1.f + __expf(-a0));
    a1 = 1.f / (1.f + __expf(-a1));
    a2 = 1.f / (1.f + __expf(-a2));
    a3 = 1.f / (1.f + __expf(-a3));
  }
  if constexpr (OBF16) {
    u32x2 o;
    o.x = (uint)f2bf(a0) | ((uint)f2bf(a1) << 16);
    o.y = (uint)f2bf(a2) | ((uint)f2bf(a3) << 16);
    __builtin_nontemporal_store(o, (u32x2*)((ushort*)out + orow));
  } else {
    f32x4v o;
    o.x = a0;
    o.y = a1;
    o.z = a2;
    o.w = a3;
    __builtin_nontemporal_store(o, (f32x4v*)((float*)out + orow));
  }
}

// ---------------------------------------------------------------------------
// Launch. ws: row_ptr(0x40000) | Wt1(0x48000) | Wt2(0x50000) | Wt3(0x54000)
// | S fp8 packed 51.2 MB (0x60000) | H bf16 102.4 MB.  ~154 MB total.
// ---------------------------------------------------------------------------
extern "C" void kernel_launch(void* const* d_in, const int* in_sizes, int n_in,
                              void* d_out, int out_size, void* d_ws, size_t ws_size,
                              hipStream_t stream) {
  const float* x = (const float*)d_in[0];
  const int* erows = (const int*)d_in[1];
  const int* ecols = (const int*)d_in[2];
  const float* evals = (const float*)d_in[3];
  const float* W1 = (const float*)d_in[4];
  const float* b1 = (const float*)d_in[5];
  const float* W2 = (const float*)d_in[6];
  const float* b2 = (const float*)d_in[7];
  const float* W3 = (const float*)d_in[8];
  const float* b3 = (const float*)d_in[9];

  char* ws = (char*)d_ws;
  int* row_ptr = (int*)ws;
  ushort* Wt1 = (ushort*)(ws + 0x40000);
  ushort* Wt2 = (ushort*)(ws + 0x48000);
  ushort* Wt3 = (ushort*)(ws + 0x50000);
  uchar* Sf8 = (uchar*)(ws + 0x60000);
  ushort* H = (ushort*)(ws + 0x60000 + (size_t)M_ROWS * 128);

  rowptr_kernel<<<(NN + 256) / 256, 256, 0, stream>>>(erows, row_ptr);
  wtrans_kernel<<<(128 * 128) / 256, 256, 0, stream>>>(W1, Wt1, 128);
  wtrans_kernel<<<(128 * 128) / 256, 256, 0, stream>>>(W2, Wt2, 128);
  wtrans_kernel<<<(64 * 128) / 256, 256, 0, stream>>>(W3, Wt3, 64);

  const dim3 sgrid128(NN / 4, NB / 2);  // pair-packed
  const dim3 sgrid64(NN / 4, NB / 4);   // quad-packed

  // Layer 1: S = x@W1 (fp8 pair-packed); H = relu(spmm(S) + b1 + x)
  gemm_mfma<128, false><<<M_ROWS / 64, 256, 0, stream>>>(x, Wt1, Sf8);
  spmm_kernel<2, 1, false, true><<<sgrid128, 256, 0, stream>>>(
      Sf8, row_ptr, ecols, evals, b1, x, H);
  // Layer 2: S = H@W2 (fp8 pair-packed); H = relu(spmm(S) + b2 + H)
  gemm_mfma<128, true><<<M_ROWS / 64, 256, 0, stream>>>(H, Wt2, Sf8);
  spmm_kernel<2, 2, false, true><<<sgrid128, 256, 0, stream>>>(
      Sf8, row_ptr, ecols, evals, b2, H, H);
  // Layer 3: S = H@W3 (fp8 quad-packed); out = sigmoid(relu(spmm(S) + b3))
  gemm_mfma<64, true><<<M_ROWS / 64, 256, 0, stream>>>(H, Wt3, Sf8);
  spmm_kernel<4, 0, true, false><<<sgrid64, 256, 0, stream>>>(
      Sf8, row_ptr, ecols, evals, b3, nullptr, (float*)d_out);
}